// Round 2
// baseline (631.296 us; speedup 1.0000x reference)
//
#include <hip/hip_runtime.h>
#include <stdint.h>

typedef unsigned int  uint32;
typedef unsigned short u16;

typedef short bfx8 __attribute__((ext_vector_type(8)));
typedef float f32x4 __attribute__((ext_vector_type(4)));
typedef float f32x2 __attribute__((ext_vector_type(2)));

// ---------- bf16 helpers ----------
__device__ __forceinline__ float b2f(u16 u) {
    union { uint32 i; float f; } v; v.i = ((uint32)u) << 16; return v.f;
}
__device__ __forceinline__ u16 f2b(float f) {
    union { float f; uint32 i; } v; v.f = f;
    uint32 u = v.i;
    return (u16)((u + 0x7fffu + ((u >> 16) & 1u)) >> 16);   // RNE
}
// split fp32 -> hi/lo bf16 pair (a ~= hi + lo, ~16 mantissa bits total)
__device__ __forceinline__ void split8(const float* __restrict__ p, bfx8& hi, bfx8& lo) {
    f32x4 a = *(const f32x4*)p;
    f32x4 b = *(const f32x4*)(p + 4);
    float x[8] = {a[0], a[1], a[2], a[3], b[0], b[1], b[2], b[3]};
#pragma unroll
    for (int j = 0; j < 8; ++j) {
        u16 h = f2b(x[j]);
        hi[j] = (short)h;
        lo[j] = (short)f2b(x[j] - b2f(h));
    }
}
__device__ __forceinline__ void split8v(const float* __restrict__ x, bfx8& hi, bfx8& lo) {
#pragma unroll
    for (int j = 0; j < 8; ++j) {
        u16 h = f2b(x[j]);
        hi[j] = (short)h;
        lo[j] = (short)f2b(x[j] - b2f(h));
    }
}

// ---------- CSR build ----------
__global__ void k_zero(int* __restrict__ p, int n) {
    int i = blockIdx.x * blockDim.x + threadIdx.x;
    if (i < n) p[i] = 0;
}

__global__ void k_deg(const int* __restrict__ row, const int* __restrict__ col,
                      int* __restrict__ deg_in, int* __restrict__ deg_out, int E) {
    int e = blockIdx.x * blockDim.x + threadIdx.x;
    if (e >= E) return;
    atomicAdd(&deg_out[row[e]], 1);
    atomicAdd(&deg_in[col[e]], 1);
}

// 2 blocks x 1024 threads: block 0 scans deg_in->off_in, block 1 deg_out->off_out
__global__ void k_scan(const int* __restrict__ deg_in, int* __restrict__ off_in,
                       const int* __restrict__ deg_out, int* __restrict__ off_out, int n) {
    const int T = 1024;
    const int* deg = (blockIdx.x == 0) ? deg_in : deg_out;
    int* off       = (blockIdx.x == 0) ? off_in : off_out;
    int t = threadIdx.x;
    int chunk = (n + T - 1) / T;
    int lo = t * chunk; if (lo > n) lo = n;
    int hi = lo + chunk; if (hi > n) hi = n;
    int s = 0;
    for (int i = lo; i < hi; ++i) s += deg[i];
    __shared__ int sm[1024];
    sm[t] = s;
    __syncthreads();
    for (int d = 1; d < T; d <<= 1) {
        int v = (t >= d) ? sm[t - d] : 0;
        __syncthreads();
        sm[t] += v;
        __syncthreads();
    }
    int run = (t == 0) ? 0 : sm[t - 1];
    for (int i = lo; i < hi; ++i) { off[i] = run; run += deg[i]; }
    if (t == T - 1) off[n] = run;
}

__global__ void k_dinv(const int* __restrict__ deg_in, float* __restrict__ dinv, int n) {
    int i = blockIdx.x * blockDim.x + threadIdx.x;
    if (i < n) dinv[i] = rsqrtf((float)(deg_in[i] + 1));   // +1 self loop; always > 0
}

__global__ void k_fill(const int* __restrict__ row, const int* __restrict__ col,
                       const int* __restrict__ off_in, const int* __restrict__ off_out,
                       int* __restrict__ cur_in, int* __restrict__ cur_out,
                       int* __restrict__ csr_src, int* __restrict__ csr_dst, int E) {
    int e = blockIdx.x * blockDim.x + threadIdx.x;
    if (e >= E) return;
    int r = row[e], c = col[e];
    int p = atomicAdd(&cur_in[c], 1);
    csr_src[off_in[c] + p] = r;
    int q = atomicAdd(&cur_out[r], 1);
    csr_dst[off_out[r] + q] = c;
}

// ---------- weight transpose + hi/lo split: WT[fo][fi] ----------
__global__ void k_transpose(const float* __restrict__ W1, const float* __restrict__ W2,
                            const float* __restrict__ W3, const float* __restrict__ fcW,
                            u16* __restrict__ WTh, u16* __restrict__ WTl) {
    int i = blockIdx.x * blockDim.x + threadIdx.x;
    float w;
    int idx;
    if (i < 3 * 16384) {
        int m = i >> 14, j = i & 16383;       // j = fo*128 + fi
        int fo = j >> 7, fi = j & 127;
        const float* W = (m == 0) ? W1 : (m == 1) ? W2 : W3;
        w = W[fi * 128 + fo];
        idx = i;
    } else if (i < 3 * 16384 + 64 * 128) {
        int j = i - 3 * 16384;                // j = fo*128 + fi, fo < 64
        int fo = j >> 7, fi = j & 127;
        w = fcW[fi * 64 + fo];
        idx = i;
    } else return;
    u16 h = f2b(w);
    WTh[idx] = h;
    WTl[idx] = f2b(w - b2f(h));
}

// ---------- C[M x 128] = (A[M x 128] @ W) * dinv[row], fp32 in/out ----------
// split-bf16 MFMA: A*B ~= Ah*Bh + Ah*Bl + Al*Bh. Wave computes 32 rows x 128 cols.
__global__ __launch_bounds__(256) void k_gemm128(
    const float* __restrict__ A, const u16* __restrict__ WTh, const u16* __restrict__ WTl,
    const float* __restrict__ dinv, float* __restrict__ C, int M) {
    const int wave = threadIdx.x >> 6;
    const int lane = threadIdx.x & 63;
    const int q = lane >> 4, l = lane & 15;
    int rbase = blockIdx.x * 128 + wave * 32;
    if (rbase >= M) return;
    int r0 = rbase + l;      if (r0 >= M) r0 = M - 1;
    int r1 = rbase + 16 + l; if (r1 >= M) r1 = M - 1;

    f32x4 acc[2][8];
#pragma unroll
    for (int i = 0; i < 2; ++i)
#pragma unroll
        for (int j = 0; j < 8; ++j) acc[i][j] = (f32x4){0.f, 0.f, 0.f, 0.f};

#pragma unroll
    for (int kc = 0; kc < 4; ++kc) {
        int k0 = kc * 32 + q * 8;
        bfx8 ah0, al0, ah1, al1;
        split8(A + (size_t)r0 * 128 + k0, ah0, al0);
        split8(A + (size_t)r1 * 128 + k0, ah1, al1);
#pragma unroll
        for (int ct = 0; ct < 8; ++ct) {
            bfx8 bh = *(const bfx8*)(WTh + (ct * 16 + l) * 128 + k0);
            bfx8 bl = *(const bfx8*)(WTl + (ct * 16 + l) * 128 + k0);
            acc[0][ct] = __builtin_amdgcn_mfma_f32_16x16x32_bf16(ah0, bh, acc[0][ct], 0, 0, 0);
            acc[0][ct] = __builtin_amdgcn_mfma_f32_16x16x32_bf16(ah0, bl, acc[0][ct], 0, 0, 0);
            acc[0][ct] = __builtin_amdgcn_mfma_f32_16x16x32_bf16(al0, bh, acc[0][ct], 0, 0, 0);
            acc[1][ct] = __builtin_amdgcn_mfma_f32_16x16x32_bf16(ah1, bh, acc[1][ct], 0, 0, 0);
            acc[1][ct] = __builtin_amdgcn_mfma_f32_16x16x32_bf16(ah1, bl, acc[1][ct], 0, 0, 0);
            acc[1][ct] = __builtin_amdgcn_mfma_f32_16x16x32_bf16(al1, bh, acc[1][ct], 0, 0, 0);
        }
    }
#pragma unroll
    for (int rs = 0; rs < 2; ++rs) {
#pragma unroll
        for (int rr = 0; rr < 4; ++rr) {
            int rw = rbase + rs * 16 + q * 4 + rr;
            if (rw < M) {
                float dv = dinv[rw];
#pragma unroll
                for (int ct = 0; ct < 8; ++ct)
                    C[(size_t)rw * 128 + ct * 16 + l] = acc[rs][ct][rr] * dv;
            }
        }
    }
}

// ---------- GCN aggregate: out[c] = relu(dinv[c]*(g[c] + sum_in g[src]) + b) ----------
// one wave per node; lane holds 2 features (float2)
__global__ __launch_bounds__(256) void k_agg(
    const f32x2* __restrict__ g, const int* __restrict__ csr_src,
    const int* __restrict__ off, const float* __restrict__ dinv,
    const f32x2* __restrict__ bias, f32x2* __restrict__ out, int n) {
    int w = (blockIdx.x * 256 + threadIdx.x) >> 6;
    if (w >= n) return;
    int lane = threadIdx.x & 63;
    f32x2 s = g[(size_t)w * 64 + lane];
    int e = off[w], e1 = off[w + 1];
    for (; e + 4 <= e1; e += 4) {
        int i0 = csr_src[e], i1 = csr_src[e + 1], i2 = csr_src[e + 2], i3 = csr_src[e + 3];
        f32x2 v0 = g[(size_t)i0 * 64 + lane];
        f32x2 v1 = g[(size_t)i1 * 64 + lane];
        f32x2 v2 = g[(size_t)i2 * 64 + lane];
        f32x2 v3 = g[(size_t)i3 * 64 + lane];
        s += v0 + v1 + v2 + v3;
    }
    for (; e < e1; ++e) s += g[(size_t)csr_src[e] * 64 + lane];
    float dc = dinv[w];
    f32x2 bb = bias[lane];
    f32x2 o;
    o[0] = fmaxf(fmaf(s[0], dc, bb[0]), 0.f);
    o[1] = fmaxf(fmaf(s[1], dc, bb[1]), 0.f);
    out[(size_t)w * 64 + lane] = o;
}

// ---------- neighbor mean: out[r] = deg>0 ? mean_{(r,c)} h[c] : h[r] ----------
__global__ __launch_bounds__(256) void k_mean(
    const f32x2* __restrict__ h, const int* __restrict__ csr_dst,
    const int* __restrict__ off, f32x2* __restrict__ out, int n) {
    int w = (blockIdx.x * 256 + threadIdx.x) >> 6;
    if (w >= n) return;
    int lane = threadIdx.x & 63;
    int e = off[w], e1 = off[w + 1];
    int d = e1 - e;
    f32x2 s = (f32x2){0.f, 0.f};
    for (; e + 4 <= e1; e += 4) {
        int i0 = csr_dst[e], i1 = csr_dst[e + 1], i2 = csr_dst[e + 2], i3 = csr_dst[e + 3];
        f32x2 v0 = h[(size_t)i0 * 64 + lane];
        f32x2 v1 = h[(size_t)i1 * 64 + lane];
        f32x2 v2 = h[(size_t)i2 * 64 + lane];
        f32x2 v3 = h[(size_t)i3 * 64 + lane];
        s += v0 + v1 + v2 + v3;
    }
    for (; e < e1; ++e) s += h[(size_t)csr_dst[e] * 64 + lane];
    f32x2 o;
    if (d > 0) {
        float inv = 1.f / (float)d;
        o[0] = s[0] * inv; o[1] = s[1] * inv;
    } else {
        o = h[(size_t)w * 64 + lane];
    }
    out[(size_t)w * 64 + lane] = o;
}

// ---------- final: out = (w0*h0 + w1*h1 + w2*h2) @ fcW + fc_b, fp32 ----------
__global__ __launch_bounds__(256) void k_final(
    const float* __restrict__ h0, const float* __restrict__ h1,
    const float* __restrict__ h2, const float* __restrict__ jkw,
    const u16* __restrict__ fcWTh, const u16* __restrict__ fcWTl,
    const float* __restrict__ fcb, float* __restrict__ out, int M) {
    float a0 = jkw[0], a1 = jkw[1], a2 = jkw[2];
    float mx = fmaxf(a0, fmaxf(a1, a2));
    float e0 = expf(a0 - mx), e1 = expf(a1 - mx), e2 = expf(a2 - mx);
    float inv = 1.f / (e0 + e1 + e2);
    float w0 = e0 * inv, w1 = e1 * inv, w2 = e2 * inv;

    const int wave = threadIdx.x >> 6;
    const int lane = threadIdx.x & 63;
    const int q = lane >> 4, l = lane & 15;
    int rbase = blockIdx.x * 128 + wave * 32;
    if (rbase >= M) return;
    int r0 = rbase + l;      if (r0 >= M) r0 = M - 1;
    int r1 = rbase + 16 + l; if (r1 >= M) r1 = M - 1;

    f32x4 acc[2][4];
#pragma unroll
    for (int i = 0; i < 2; ++i)
#pragma unroll
        for (int j = 0; j < 4; ++j) acc[i][j] = (f32x4){0.f, 0.f, 0.f, 0.f};

#pragma unroll
    for (int kc = 0; kc < 4; ++kc) {
        int k0 = kc * 32 + q * 8;
        bfx8 ah[2], al[2];
        const int rr2[2] = {r0, r1};
#pragma unroll
        for (int half = 0; half < 2; ++half) {
            size_t o = (size_t)rr2[half] * 128 + k0;
            float xx[8];
#pragma unroll
            for (int j = 0; j < 8; ++j)
                xx[j] = w0 * h0[o + j] + w1 * h1[o + j] + w2 * h2[o + j];
            split8v(xx, ah[half], al[half]);
        }
#pragma unroll
        for (int ct = 0; ct < 4; ++ct) {
            bfx8 bh = *(const bfx8*)(fcWTh + (ct * 16 + l) * 128 + k0);
            bfx8 bl = *(const bfx8*)(fcWTl + (ct * 16 + l) * 128 + k0);
#pragma unroll
            for (int half = 0; half < 2; ++half) {
                acc[half][ct] = __builtin_amdgcn_mfma_f32_16x16x32_bf16(ah[half], bh, acc[half][ct], 0, 0, 0);
                acc[half][ct] = __builtin_amdgcn_mfma_f32_16x16x32_bf16(ah[half], bl, acc[half][ct], 0, 0, 0);
                acc[half][ct] = __builtin_amdgcn_mfma_f32_16x16x32_bf16(al[half], bh, acc[half][ct], 0, 0, 0);
            }
        }
    }
#pragma unroll
    for (int rs = 0; rs < 2; ++rs) {
#pragma unroll
        for (int rr = 0; rr < 4; ++rr) {
            int rw = rbase + rs * 16 + q * 4 + rr;
            if (rw < M) {
#pragma unroll
                for (int ct = 0; ct < 4; ++ct) {
                    int cc = ct * 16 + l;
                    out[(size_t)rw * 64 + cc] = acc[rs][ct][rr] + fcb[cc];
                }
            }
        }
    }
}

extern "C" void kernel_launch(void* const* d_in, const int* in_sizes, int n_in,
                              void* d_out, int out_size, void* d_ws, size_t ws_size,
                              hipStream_t stream) {
    const int N = in_sizes[0] / 128;   // 50000
    const int E = in_sizes[1] / 2;     // 800000

    const float* x    = (const float*)d_in[0];
    const int* row    = (const int*)d_in[1];
    const int* col    = row + E;
    const float* W1   = (const float*)d_in[2];
    const float* b1   = (const float*)d_in[3];
    const float* W2   = (const float*)d_in[4];
    const float* b2   = (const float*)d_in[5];
    const float* W3   = (const float*)d_in[6];
    const float* b3   = (const float*)d_in[7];
    const float* jkw  = (const float*)d_in[8];
    const float* fcW  = (const float*)d_in[9];
    const float* fcb  = (const float*)d_in[10];
    float* outp       = (float*)d_out;

    char* ws = (char*)d_ws;
    size_t off = 0;
    auto alloc = [&](size_t bytes) -> char* {
        char* p = ws + off;
        off += (bytes + 255) & ~(size_t)255;
        return p;
    };
    int* deg_in  = (int*)alloc((size_t)4 * N * sizeof(int)); // deg_in|deg_out|cur_in|cur_out
    int* deg_out = deg_in + N;
    int* cur_in  = deg_in + 2 * N;
    int* cur_out = deg_in + 3 * N;
    int* off_in  = (int*)alloc((size_t)(N + 1) * sizeof(int));
    int* off_out = (int*)alloc((size_t)(N + 1) * sizeof(int));
    int* csr_src = (int*)alloc((size_t)E * sizeof(int));
    int* csr_dst = (int*)alloc((size_t)E * sizeof(int));
    float* dinv  = (float*)alloc((size_t)N * sizeof(float));
    const int WTN = 3 * 16384 + 8192;
    u16* WTh = (u16*)alloc((size_t)WTN * sizeof(u16));
    u16* WTl = (u16*)alloc((size_t)WTN * sizeof(u16));
    float* bufA = (float*)alloc((size_t)N * 128 * sizeof(float));
    float* h0   = (float*)alloc((size_t)N * 128 * sizeof(float));
    float* h1   = (float*)alloc((size_t)N * 128 * sizeof(float));
    float* h2   = (float*)alloc((size_t)N * 128 * sizeof(float));

    const int B = 256;
    k_zero<<<(4 * N + B - 1) / B, B, 0, stream>>>(deg_in, 4 * N);
    k_transpose<<<(WTN + B - 1) / B, B, 0, stream>>>(W1, W2, W3, fcW, WTh, WTl);
    k_deg<<<(E + B - 1) / B, B, 0, stream>>>(row, col, deg_in, deg_out, E);
    k_scan<<<2, 1024, 0, stream>>>(deg_in, off_in, deg_out, off_out, N);
    k_dinv<<<(N + B - 1) / B, B, 0, stream>>>(deg_in, dinv, N);
    k_fill<<<(E + B - 1) / B, B, 0, stream>>>(row, col, off_in, off_out,
                                              cur_in, cur_out, csr_src, csr_dst, E);

    dim3 gg((N + 127) / 128);
    int aggG = (N + 3) / 4;   // 4 waves/block, 1 node/wave

    // layer 0 (h1 used as temp for pre-mean activations)
    k_gemm128<<<gg, B, 0, stream>>>(x, WTh, WTl, dinv, bufA, N);
    k_agg<<<aggG, B, 0, stream>>>((const f32x2*)bufA, csr_src, off_in, dinv,
                                  (const f32x2*)b1, (f32x2*)h1, N);
    k_mean<<<aggG, B, 0, stream>>>((const f32x2*)h1, csr_dst, off_out, (f32x2*)h0, N);
    // layer 1
    k_gemm128<<<gg, B, 0, stream>>>(h0, WTh + 16384, WTl + 16384, dinv, bufA, N);
    k_agg<<<aggG, B, 0, stream>>>((const f32x2*)bufA, csr_src, off_in, dinv,
                                  (const f32x2*)b2, (f32x2*)h1, N);
    // layer 2
    k_gemm128<<<gg, B, 0, stream>>>(h1, WTh + 2 * 16384, WTl + 2 * 16384, dinv, bufA, N);
    k_agg<<<aggG, B, 0, stream>>>((const f32x2*)bufA, csr_src, off_in, dinv,
                                  (const f32x2*)b3, (f32x2*)h2, N);
    // JK combine + final linear
    k_final<<<gg, B, 0, stream>>>(h0, h1, h2, jkw, WTh + 3 * 16384, WTl + 3 * 16384,
                                  fcb, outp, N);
}

// Round 3
// 523.960 us; speedup vs baseline: 1.2049x; 1.2049x over previous
//
#include <hip/hip_runtime.h>
#include <stdint.h>

typedef unsigned int  uint32;
typedef unsigned short u16;

typedef short bfx8 __attribute__((ext_vector_type(8)));
typedef float f32x4 __attribute__((ext_vector_type(4)));
typedef float f32x2 __attribute__((ext_vector_type(2)));

// ---------- bf16 helpers ----------
__device__ __forceinline__ float b2f(u16 u) {
    union { uint32 i; float f; } v; v.i = ((uint32)u) << 16; return v.f;
}
__device__ __forceinline__ u16 f2b(float f) {
    union { float f; uint32 i; } v; v.f = f;
    uint32 u = v.i;
    return (u16)((u + 0x7fffu + ((u >> 16) & 1u)) >> 16);   // RNE
}
__device__ __forceinline__ float blo(uint32 u) {            // low u16 = even feat
    union { uint32 i; float f; } v; v.i = u << 16; return v.f;
}
__device__ __forceinline__ float bhi(uint32 u) {            // high u16 = odd feat
    union { uint32 i; float f; } v; v.i = u & 0xffff0000u; return v.f;
}
__device__ __forceinline__ uint32 packbf(float a, float b) {
    return (uint32)f2b(a) | ((uint32)f2b(b) << 16);
}
// split fp32 -> hi/lo bf16 pair (a ~= hi + lo)
__device__ __forceinline__ void split8(const float* __restrict__ p, bfx8& hi, bfx8& lo) {
    f32x4 a = *(const f32x4*)p;
    f32x4 b = *(const f32x4*)(p + 4);
    float x[8] = {a[0], a[1], a[2], a[3], b[0], b[1], b[2], b[3]};
#pragma unroll
    for (int j = 0; j < 8; ++j) {
        u16 h = f2b(x[j]);
        hi[j] = (short)h;
        lo[j] = (short)f2b(x[j] - b2f(h));
    }
}
__device__ __forceinline__ void split8v(const float* __restrict__ x, bfx8& hi, bfx8& lo) {
#pragma unroll
    for (int j = 0; j < 8; ++j) {
        u16 h = f2b(x[j]);
        hi[j] = (short)h;
        lo[j] = (short)f2b(x[j] - b2f(h));
    }
}

// ---------- fused: weight transpose+split  ||  degree histogram ----------
__global__ void k_pre(const float* __restrict__ W1, const float* __restrict__ W2,
                      const float* __restrict__ W3, const float* __restrict__ fcW,
                      u16* __restrict__ WTh, u16* __restrict__ WTl,
                      const int* __restrict__ row, const int* __restrict__ col,
                      int* __restrict__ deg_in, int* __restrict__ deg_out,
                      int E, int WTN) {
    int i = blockIdx.x * 256 + threadIdx.x;
    if (i < WTN) {
        float w;
        if (i < 3 * 16384) {
            int m = i >> 14, j = i & 16383;     // j = fo*128 + fi
            int fo = j >> 7, fi = j & 127;
            const float* W = (m == 0) ? W1 : (m == 1) ? W2 : W3;
            w = W[fi * 128 + fo];
        } else {
            int j = i - 3 * 16384;
            int fo = j >> 7, fi = j & 127;
            w = fcW[fi * 64 + fo];
        }
        u16 h = f2b(w);
        WTh[i] = h;
        WTl[i] = f2b(w - b2f(h));
        return;
    }
    int e = i - WTN;
    if (e < E) {
        atomicAdd(&deg_out[row[e]], 1);
        atomicAdd(&deg_in[col[e]], 1);
    }
}

// ---------- blocks 0,1: exclusive scans; blocks >=2: dinv ----------
__global__ void k_scan2(const int* __restrict__ deg_in, int* __restrict__ off_in,
                        const int* __restrict__ deg_out, int* __restrict__ off_out,
                        float* __restrict__ dinv, int n) {
    if (blockIdx.x >= 2) {
        int i = ((int)blockIdx.x - 2) * 1024 + threadIdx.x;
        if (i < n) dinv[i] = rsqrtf((float)(deg_in[i] + 1));   // +1 self loop
        return;
    }
    const int T = 1024;
    const int* deg = (blockIdx.x == 0) ? deg_in : deg_out;
    int* off       = (blockIdx.x == 0) ? off_in : off_out;
    int t = threadIdx.x;
    int chunk = (n + T - 1) / T;
    int lo = t * chunk; if (lo > n) lo = n;
    int hi = lo + chunk; if (hi > n) hi = n;
    int s = 0;
    for (int i = lo; i < hi; ++i) s += deg[i];
    __shared__ int sm[1024];
    sm[t] = s;
    __syncthreads();
    for (int d = 1; d < T; d <<= 1) {
        int v = (t >= d) ? sm[t - d] : 0;
        __syncthreads();
        sm[t] += v;
        __syncthreads();
    }
    int run = (t == 0) ? 0 : sm[t - 1];
    for (int i = lo; i < hi; ++i) { off[i] = run; run += deg[i]; }
    if (t == T - 1) off[n] = run;
}

// ---------- gemm body: g[M x 128] = (A @ W) * dinv[row], bf16 out ----------
__device__ __forceinline__ void gemm128_body(
    const float* __restrict__ A, const u16* __restrict__ WTh, const u16* __restrict__ WTl,
    const float* __restrict__ dinv, u16* __restrict__ G, int M, int blk) {
    const int wave = threadIdx.x >> 6;
    const int lane = threadIdx.x & 63;
    const int q = lane >> 4, l = lane & 15;
    int rbase = blk * 128 + wave * 32;
    if (rbase >= M) return;
    int r0 = rbase + l;      if (r0 >= M) r0 = M - 1;
    int r1 = rbase + 16 + l; if (r1 >= M) r1 = M - 1;

    f32x4 acc[2][8];
#pragma unroll
    for (int i = 0; i < 2; ++i)
#pragma unroll
        for (int j = 0; j < 8; ++j) acc[i][j] = (f32x4){0.f, 0.f, 0.f, 0.f};

#pragma unroll
    for (int kc = 0; kc < 4; ++kc) {
        int k0 = kc * 32 + q * 8;
        bfx8 ah0, al0, ah1, al1;
        split8(A + (size_t)r0 * 128 + k0, ah0, al0);
        split8(A + (size_t)r1 * 128 + k0, ah1, al1);
#pragma unroll
        for (int ct = 0; ct < 8; ++ct) {
            bfx8 bh = *(const bfx8*)(WTh + (ct * 16 + l) * 128 + k0);
            bfx8 bl = *(const bfx8*)(WTl + (ct * 16 + l) * 128 + k0);
            acc[0][ct] = __builtin_amdgcn_mfma_f32_16x16x32_bf16(ah0, bh, acc[0][ct], 0, 0, 0);
            acc[0][ct] = __builtin_amdgcn_mfma_f32_16x16x32_bf16(ah0, bl, acc[0][ct], 0, 0, 0);
            acc[0][ct] = __builtin_amdgcn_mfma_f32_16x16x32_bf16(al0, bh, acc[0][ct], 0, 0, 0);
            acc[1][ct] = __builtin_amdgcn_mfma_f32_16x16x32_bf16(ah1, bh, acc[1][ct], 0, 0, 0);
            acc[1][ct] = __builtin_amdgcn_mfma_f32_16x16x32_bf16(ah1, bl, acc[1][ct], 0, 0, 0);
            acc[1][ct] = __builtin_amdgcn_mfma_f32_16x16x32_bf16(al1, bh, acc[1][ct], 0, 0, 0);
        }
    }
#pragma unroll
    for (int rs = 0; rs < 2; ++rs) {
#pragma unroll
        for (int rr = 0; rr < 4; ++rr) {
            int rw = rbase + rs * 16 + q * 4 + rr;
            if (rw < M) {
                float dv = dinv[rw];
#pragma unroll
                for (int ct = 0; ct < 8; ++ct)
                    G[(size_t)rw * 128 + ct * 16 + l] = f2b(acc[rs][ct][rr] * dv);
            }
        }
    }
}

__global__ __launch_bounds__(256) void k_gemm128(
    const float* __restrict__ A, const u16* __restrict__ WTh, const u16* __restrict__ WTl,
    const float* __restrict__ dinv, u16* __restrict__ G, int M) {
    gemm128_body(A, WTh, WTl, dinv, G, M, blockIdx.x);
}

// ---------- fused: gemm0 (blocks < Gg)  ||  CSR fill (blocks >= Gg) ----------
__global__ __launch_bounds__(256) void k_fill_gemm0(
    const float* __restrict__ A, const u16* __restrict__ WTh, const u16* __restrict__ WTl,
    const float* __restrict__ dinv, u16* __restrict__ G, int M, int Gg,
    const int* __restrict__ row, const int* __restrict__ col,
    const int* __restrict__ off_in, const int* __restrict__ off_out,
    int* __restrict__ cur_in, int* __restrict__ cur_out,
    u16* __restrict__ csr_src, u16* __restrict__ csr_dst, int E) {
    if ((int)blockIdx.x >= Gg) {
        int e = ((int)blockIdx.x - Gg) * 256 + threadIdx.x;
        if (e < E) {
            int r = row[e], c = col[e];
            int p = atomicAdd(&cur_in[c], 1);
            csr_src[off_in[c] + p] = (u16)r;
            int q = atomicAdd(&cur_out[r], 1);
            csr_dst[off_out[r] + q] = (u16)c;
        }
        return;
    }
    gemm128_body(A, WTh, WTl, dinv, G, M, blockIdx.x);
}

// ---------- GCN aggregate over bf16 g: out[c] = relu(dinv[c]*(g[c]+sum g[src]) + b) ----
// one wave per node; lane holds feats {2*lane, 2*lane+1} packed in uint32
template <bool OUT_BF16>
__global__ __launch_bounds__(256) void k_agg(
    const uint32* __restrict__ g, const u16* __restrict__ csr_src,
    const int* __restrict__ off, const float* __restrict__ dinv,
    const f32x2* __restrict__ bias, void* __restrict__ outp, int n) {
    int w = (blockIdx.x * 256 + threadIdx.x) >> 6;
    if (w >= n) return;
    int lane = threadIdx.x & 63;
    uint32 sv = g[(size_t)w * 64 + lane];
    float s0 = blo(sv), s1 = bhi(sv);
    int e = off[w], e1 = off[w + 1];
    for (; e + 4 <= e1; e += 4) {
        int i0 = csr_src[e], i1 = csr_src[e + 1], i2 = csr_src[e + 2], i3 = csr_src[e + 3];
        uint32 v0 = g[(size_t)i0 * 64 + lane];
        uint32 v1 = g[(size_t)i1 * 64 + lane];
        uint32 v2 = g[(size_t)i2 * 64 + lane];
        uint32 v3 = g[(size_t)i3 * 64 + lane];
        s0 += blo(v0) + blo(v1) + blo(v2) + blo(v3);
        s1 += bhi(v0) + bhi(v1) + bhi(v2) + bhi(v3);
    }
    for (; e < e1; ++e) {
        uint32 v = g[(size_t)csr_src[e] * 64 + lane];
        s0 += blo(v); s1 += bhi(v);
    }
    float dc = dinv[w];
    f32x2 bb = bias[lane];
    float o0 = fmaxf(fmaf(s0, dc, bb[0]), 0.f);
    float o1 = fmaxf(fmaf(s1, dc, bb[1]), 0.f);
    if (OUT_BF16) {
        ((uint32*)outp)[(size_t)w * 64 + lane] = packbf(o0, o1);
    } else {
        ((f32x2*)outp)[(size_t)w * 64 + lane] = (f32x2){o0, o1};
    }
}

// ---------- neighbor mean over bf16 t: out fp32 ----------
__global__ __launch_bounds__(256) void k_mean(
    const uint32* __restrict__ h, const u16* __restrict__ csr_dst,
    const int* __restrict__ off, f32x2* __restrict__ out, int n) {
    int w = (blockIdx.x * 256 + threadIdx.x) >> 6;
    if (w >= n) return;
    int lane = threadIdx.x & 63;
    int e = off[w], e1 = off[w + 1];
    int d = e1 - e;
    float s0 = 0.f, s1 = 0.f;
    for (; e + 4 <= e1; e += 4) {
        int i0 = csr_dst[e], i1 = csr_dst[e + 1], i2 = csr_dst[e + 2], i3 = csr_dst[e + 3];
        uint32 v0 = h[(size_t)i0 * 64 + lane];
        uint32 v1 = h[(size_t)i1 * 64 + lane];
        uint32 v2 = h[(size_t)i2 * 64 + lane];
        uint32 v3 = h[(size_t)i3 * 64 + lane];
        s0 += blo(v0) + blo(v1) + blo(v2) + blo(v3);
        s1 += bhi(v0) + bhi(v1) + bhi(v2) + bhi(v3);
    }
    for (; e < e1; ++e) {
        uint32 v = h[(size_t)csr_dst[e] * 64 + lane];
        s0 += blo(v); s1 += bhi(v);
    }
    f32x2 o;
    if (d > 0) {
        float inv = 1.f / (float)d;
        o[0] = s0 * inv; o[1] = s1 * inv;
    } else {
        uint32 sv = h[(size_t)w * 64 + lane];
        o[0] = blo(sv); o[1] = bhi(sv);
    }
    out[(size_t)w * 64 + lane] = o;
}

// ---------- final: out = (w0*h0 + w1*h1 + w2*h2) @ fcW + fc_b, fp32 ----------
__global__ __launch_bounds__(256) void k_final(
    const float* __restrict__ h0, const float* __restrict__ h1,
    const float* __restrict__ h2, const float* __restrict__ jkw,
    const u16* __restrict__ fcWTh, const u16* __restrict__ fcWTl,
    const float* __restrict__ fcb, float* __restrict__ out, int M) {
    float a0 = jkw[0], a1 = jkw[1], a2 = jkw[2];
    float mx = fmaxf(a0, fmaxf(a1, a2));
    float e0 = expf(a0 - mx), e1 = expf(a1 - mx), e2 = expf(a2 - mx);
    float inv = 1.f / (e0 + e1 + e2);
    float w0 = e0 * inv, w1 = e1 * inv, w2 = e2 * inv;

    const int wave = threadIdx.x >> 6;
    const int lane = threadIdx.x & 63;
    const int q = lane >> 4, l = lane & 15;
    int rbase = blockIdx.x * 128 + wave * 32;
    if (rbase >= M) return;
    int r0 = rbase + l;      if (r0 >= M) r0 = M - 1;
    int r1 = rbase + 16 + l; if (r1 >= M) r1 = M - 1;

    f32x4 acc[2][4];
#pragma unroll
    for (int i = 0; i < 2; ++i)
#pragma unroll
        for (int j = 0; j < 4; ++j) acc[i][j] = (f32x4){0.f, 0.f, 0.f, 0.f};

#pragma unroll
    for (int kc = 0; kc < 4; ++kc) {
        int k0 = kc * 32 + q * 8;
        bfx8 ah[2], al[2];
        const int rr2[2] = {r0, r1};
#pragma unroll
        for (int half = 0; half < 2; ++half) {
            size_t o = (size_t)rr2[half] * 128 + k0;
            float xx[8];
#pragma unroll
            for (int j = 0; j < 8; ++j)
                xx[j] = w0 * h0[o + j] + w1 * h1[o + j] + w2 * h2[o + j];
            split8v(xx, ah[half], al[half]);
        }
#pragma unroll
        for (int ct = 0; ct < 4; ++ct) {
            bfx8 bh = *(const bfx8*)(fcWTh + (ct * 16 + l) * 128 + k0);
            bfx8 bl = *(const bfx8*)(fcWTl + (ct * 16 + l) * 128 + k0);
#pragma unroll
            for (int half = 0; half < 2; ++half) {
                acc[half][ct] = __builtin_amdgcn_mfma_f32_16x16x32_bf16(ah[half], bh, acc[half][ct], 0, 0, 0);
                acc[half][ct] = __builtin_amdgcn_mfma_f32_16x16x32_bf16(ah[half], bl, acc[half][ct], 0, 0, 0);
                acc[half][ct] = __builtin_amdgcn_mfma_f32_16x16x32_bf16(al[half], bh, acc[half][ct], 0, 0, 0);
            }
        }
    }
#pragma unroll
    for (int rs = 0; rs < 2; ++rs) {
#pragma unroll
        for (int rr = 0; rr < 4; ++rr) {
            int rw = rbase + rs * 16 + q * 4 + rr;
            if (rw < M) {
#pragma unroll
                for (int ct = 0; ct < 4; ++ct) {
                    int cc = ct * 16 + l;
                    out[(size_t)rw * 64 + cc] = acc[rs][ct][rr] + fcb[cc];
                }
            }
        }
    }
}

extern "C" void kernel_launch(void* const* d_in, const int* in_sizes, int n_in,
                              void* d_out, int out_size, void* d_ws, size_t ws_size,
                              hipStream_t stream) {
    const int N = in_sizes[0] / 128;   // 50000
    const int E = in_sizes[1] / 2;     // 800000

    const float* x    = (const float*)d_in[0];
    const int* row    = (const int*)d_in[1];
    const int* col    = row + E;
    const float* W1   = (const float*)d_in[2];
    const float* b1   = (const float*)d_in[3];
    const float* W2   = (const float*)d_in[4];
    const float* b2   = (const float*)d_in[5];
    const float* W3   = (const float*)d_in[6];
    const float* b3   = (const float*)d_in[7];
    const float* jkw  = (const float*)d_in[8];
    const float* fcW  = (const float*)d_in[9];
    const float* fcb  = (const float*)d_in[10];
    float* outp       = (float*)d_out;

    char* ws = (char*)d_ws;
    size_t off = 0;
    auto alloc = [&](size_t bytes) -> char* {
        char* p = ws + off;
        off += (bytes + 255) & ~(size_t)255;
        return p;
    };
    int* deg_in  = (int*)alloc((size_t)4 * N * sizeof(int)); // deg_in|deg_out|cur_in|cur_out
    int* deg_out = deg_in + N;
    int* cur_in  = deg_in + 2 * N;
    int* cur_out = deg_in + 3 * N;
    int* off_in  = (int*)alloc((size_t)(N + 1) * sizeof(int));
    int* off_out = (int*)alloc((size_t)(N + 1) * sizeof(int));
    u16* csr_src = (u16*)alloc((size_t)E * sizeof(u16));
    u16* csr_dst = (u16*)alloc((size_t)E * sizeof(u16));
    float* dinv  = (float*)alloc((size_t)N * sizeof(float));
    const int WTN = 3 * 16384 + 8192;
    u16* WTh = (u16*)alloc((size_t)WTN * sizeof(u16));
    u16* WTl = (u16*)alloc((size_t)WTN * sizeof(u16));
    u16* gbuf = (u16*)alloc((size_t)N * 128 * sizeof(u16));  // bf16 gemm out (reused x3)
    u16* t0   = (u16*)alloc((size_t)N * 128 * sizeof(u16));  // bf16 pre-mean temp
    float* h0 = (float*)alloc((size_t)N * 128 * sizeof(float));
    float* h1 = (float*)alloc((size_t)N * 128 * sizeof(float));
    float* h2 = (float*)alloc((size_t)N * 128 * sizeof(float));

    hipMemsetAsync(deg_in, 0, (size_t)4 * N * sizeof(int), stream);

    const int B = 256;
    int Gt = (WTN + E + B - 1) / B;
    k_pre<<<Gt, B, 0, stream>>>(W1, W2, W3, fcW, WTh, WTl, row, col, deg_in, deg_out, E, WTN);
    k_scan2<<<2 + (N + 1023) / 1024, 1024, 0, stream>>>(deg_in, off_in, deg_out, off_out, dinv, N);

    int Gg = (N + 127) / 128;            // gemm blocks
    int Gf = (E + B - 1) / B;            // fill blocks
    int aggG = (N + 3) / 4;              // 4 waves/block, 1 node/wave

    // layer 0: gemm0 overlapped with CSR fill (independent work)
    k_fill_gemm0<<<Gg + Gf, B, 0, stream>>>(x, WTh, WTl, dinv, gbuf, N, Gg,
                                            row, col, off_in, off_out,
                                            cur_in, cur_out, csr_src, csr_dst, E);
    k_agg<true><<<aggG, B, 0, stream>>>((const uint32*)gbuf, csr_src, off_in, dinv,
                                        (const f32x2*)b1, (void*)t0, N);
    k_mean<<<aggG, B, 0, stream>>>((const uint32*)t0, csr_dst, off_out, (f32x2*)h0, N);
    // layer 1
    k_gemm128<<<Gg, B, 0, stream>>>(h0, WTh + 16384, WTl + 16384, dinv, gbuf, N);
    k_agg<false><<<aggG, B, 0, stream>>>((const uint32*)gbuf, csr_src, off_in, dinv,
                                         (const f32x2*)b2, (void*)h1, N);
    // layer 2
    k_gemm128<<<Gg, B, 0, stream>>>(h1, WTh + 2 * 16384, WTl + 2 * 16384, dinv, gbuf, N);
    k_agg<false><<<aggG, B, 0, stream>>>((const uint32*)gbuf, csr_src, off_in, dinv,
                                         (const f32x2*)b3, (void*)h2, N);
    // JK combine + final linear
    k_final<<<Gg, B, 0, stream>>>(h0, h1, h2, jkw, WTh + 3 * 16384, WTl + 3 * 16384,
                                  fcb, outp, N);
}

// Round 4
// 389.828 us; speedup vs baseline: 1.6194x; 1.3441x over previous
//
#include <hip/hip_runtime.h>
#include <stdint.h>

typedef unsigned int  uint32;
typedef unsigned short u16;

typedef short bfx8 __attribute__((ext_vector_type(8)));
typedef float f32x4 __attribute__((ext_vector_type(4)));
typedef float f32x2 __attribute__((ext_vector_type(2)));

#define NBP 256          // padded bucket count (N <= 65536)
#define CH  2048         // edges per partition chunk

// ---------- bf16 helpers ----------
__device__ __forceinline__ float b2f(u16 u) {
    union { uint32 i; float f; } v; v.i = ((uint32)u) << 16; return v.f;
}
__device__ __forceinline__ u16 f2b(float f) {
    union { float f; uint32 i; } v; v.f = f;
    uint32 u = v.i;
    return (u16)((u + 0x7fffu + ((u >> 16) & 1u)) >> 16);   // RNE
}
__device__ __forceinline__ float blo(uint32 u) {
    union { uint32 i; float f; } v; v.i = u << 16; return v.f;
}
__device__ __forceinline__ float bhi(uint32 u) {
    union { uint32 i; float f; } v; v.i = u & 0xffff0000u; return v.f;
}
__device__ __forceinline__ uint32 packbf(float a, float b) {
    return (uint32)f2b(a) | ((uint32)f2b(b) << 16);
}
__device__ __forceinline__ void split8(const float* __restrict__ p, bfx8& hi, bfx8& lo) {
    f32x4 a = *(const f32x4*)p;
    f32x4 b = *(const f32x4*)(p + 4);
    float x[8] = {a[0], a[1], a[2], a[3], b[0], b[1], b[2], b[3]};
#pragma unroll
    for (int j = 0; j < 8; ++j) {
        u16 h = f2b(x[j]);
        hi[j] = (short)h;
        lo[j] = (short)f2b(x[j] - b2f(h));
    }
}
__device__ __forceinline__ void split8v(const float* __restrict__ x, bfx8& hi, bfx8& lo) {
#pragma unroll
    for (int j = 0; j < 8; ++j) {
        u16 h = f2b(x[j]);
        hi[j] = (short)h;
        lo[j] = (short)f2b(x[j] - b2f(h));
    }
}

// ---------- pass A: bucket histograms + per-node deg_in || weight split ----------
__global__ __launch_bounds__(256) void k_preA(
    const int* __restrict__ row, const int* __restrict__ col, int E, int Gh,
    int* __restrict__ cntC, int* __restrict__ cntR, int* __restrict__ deg_in,
    const float* __restrict__ W1, const float* __restrict__ W2,
    const float* __restrict__ W3, const float* __restrict__ fcW,
    u16* __restrict__ WTh, u16* __restrict__ WTl, int WTN) {
    if ((int)blockIdx.x < Gh) {
        __shared__ int hc[NBP], hr[NBP];
        int t = threadIdx.x;
        hc[t] = 0; hr[t] = 0;
        __syncthreads();
        int base = blockIdx.x * CH;
        int n = E - base; if (n > CH) n = CH;
        for (int i = t; i < n; i += 256) {
            int r = row[base + i], c = col[base + i];
            atomicAdd(&hc[c >> 8], 1);
            atomicAdd(&hr[r >> 8], 1);
            atomicAdd(&deg_in[c], 1);
        }
        __syncthreads();
        if (hc[t]) atomicAdd(&cntC[t], hc[t]);
        if (hr[t]) atomicAdd(&cntR[t], hr[t]);
        return;
    }
    int i = ((int)blockIdx.x - Gh) * 256 + threadIdx.x;
    if (i >= WTN) return;
    float w;
    if (i < 3 * 16384) {
        int m = i >> 14, j = i & 16383;     // j = fo*128 + fi
        int fo = j >> 7, fi = j & 127;
        const float* W = (m == 0) ? W1 : (m == 1) ? W2 : W3;
        w = W[fi * 128 + fo];
    } else {
        int j = i - 3 * 16384;
        int fo = j >> 7, fi = j & 127;
        w = fcW[fi * 64 + fo];
    }
    u16 h = f2b(w);
    WTh[i] = h;
    WTl[i] = f2b(w - b2f(h));
}

// ---------- pass B: block 0 scans bucket counts; blocks >=1 compute dinv ----------
__global__ __launch_bounds__(256) void k_scanB(
    const int* __restrict__ cntC, const int* __restrict__ cntR,
    int* __restrict__ bOffC, int* __restrict__ bOffR,
    int* __restrict__ curC, int* __restrict__ curR,
    const int* __restrict__ deg_in, float* __restrict__ dinv, int NB, int N) {
    int t = threadIdx.x;
    if (blockIdx.x >= 1) {
        int i = ((int)blockIdx.x - 1) * 256 + t;
        if (i < N) dinv[i] = rsqrtf((float)(deg_in[i] + 1));   // +1 self loop
        return;
    }
    __shared__ int sm[NBP];
    for (int m = 0; m < 2; ++m) {
        const int* cnt = m ? cntR : cntC;
        int* bOff = m ? bOffR : bOffC;
        int* cur  = m ? curR  : curC;
        int v = (t < NB) ? cnt[t] : 0;
        sm[t] = v;
        __syncthreads();
        for (int d = 1; d < 256; d <<= 1) {
            int u = (t >= d) ? sm[t - d] : 0;
            __syncthreads();
            sm[t] += u;
            __syncthreads();
        }
        int ex = (t == 0) ? 0 : sm[t - 1];
        if (t <= NB) bOff[t] = ex;
        cur[t] = ex;
        __syncthreads();
    }
}

// ---------- gemm body: G[M x 128] = (A @ W) * dinv[row], bf16 out ----------
__device__ __forceinline__ void gemm128_body(
    const float* __restrict__ A, const u16* __restrict__ WTh, const u16* __restrict__ WTl,
    const float* __restrict__ dinv, u16* __restrict__ G, int M, int blk) {
    const int wave = threadIdx.x >> 6;
    const int lane = threadIdx.x & 63;
    const int q = lane >> 4, l = lane & 15;
    int rbase = blk * 128 + wave * 32;
    if (rbase >= M) return;
    int r0 = rbase + l;      if (r0 >= M) r0 = M - 1;
    int r1 = rbase + 16 + l; if (r1 >= M) r1 = M - 1;

    f32x4 acc[2][8];
#pragma unroll
    for (int i = 0; i < 2; ++i)
#pragma unroll
        for (int j = 0; j < 8; ++j) acc[i][j] = (f32x4){0.f, 0.f, 0.f, 0.f};

#pragma unroll
    for (int kc = 0; kc < 4; ++kc) {
        int k0 = kc * 32 + q * 8;
        bfx8 ah0, al0, ah1, al1;
        split8(A + (size_t)r0 * 128 + k0, ah0, al0);
        split8(A + (size_t)r1 * 128 + k0, ah1, al1);
#pragma unroll
        for (int ct = 0; ct < 8; ++ct) {
            bfx8 bh = *(const bfx8*)(WTh + (ct * 16 + l) * 128 + k0);
            bfx8 bl = *(const bfx8*)(WTl + (ct * 16 + l) * 128 + k0);
            acc[0][ct] = __builtin_amdgcn_mfma_f32_16x16x32_bf16(ah0, bh, acc[0][ct], 0, 0, 0);
            acc[0][ct] = __builtin_amdgcn_mfma_f32_16x16x32_bf16(ah0, bl, acc[0][ct], 0, 0, 0);
            acc[0][ct] = __builtin_amdgcn_mfma_f32_16x16x32_bf16(al0, bh, acc[0][ct], 0, 0, 0);
            acc[1][ct] = __builtin_amdgcn_mfma_f32_16x16x32_bf16(ah1, bh, acc[1][ct], 0, 0, 0);
            acc[1][ct] = __builtin_amdgcn_mfma_f32_16x16x32_bf16(ah1, bl, acc[1][ct], 0, 0, 0);
            acc[1][ct] = __builtin_amdgcn_mfma_f32_16x16x32_bf16(al1, bh, acc[1][ct], 0, 0, 0);
        }
    }
#pragma unroll
    for (int rs = 0; rs < 2; ++rs) {
#pragma unroll
        for (int rr = 0; rr < 4; ++rr) {
            int rw = rbase + rs * 16 + q * 4 + rr;
            if (rw < M) {
                float dv = dinv[rw];
#pragma unroll
                for (int ct = 0; ct < 8; ++ct)
                    G[(size_t)rw * 128 + ct * 16 + l] = f2b(acc[rs][ct][rr] * dv);
            }
        }
    }
}

__global__ __launch_bounds__(256) void k_gemm128(
    const float* __restrict__ A, const u16* __restrict__ WTh, const u16* __restrict__ WTl,
    const float* __restrict__ dinv, u16* __restrict__ G, int M) {
    gemm128_body(A, WTh, WTl, dinv, G, M, blockIdx.x);
}

// ---------- pass C: bucket partition (blocks < Gc) || gemm0 ----------
__global__ __launch_bounds__(256) void k_partC_gemm0(
    const int* __restrict__ row, const int* __restrict__ col, int E, int Gc,
    int* __restrict__ curC, int* __restrict__ curR,
    uint32* __restrict__ partC, uint32* __restrict__ partR,
    const float* __restrict__ A, const u16* __restrict__ WTh, const u16* __restrict__ WTl,
    const float* __restrict__ dinv, u16* __restrict__ G, int M) {
    if ((int)blockIdx.x >= Gc) {
        gemm128_body(A, WTh, WTl, dinv, G, M, (int)blockIdx.x - Gc);
        return;
    }
    __shared__ uint32 staged[CH];
    __shared__ int cnt[NBP], excl[NBP], run[NBP], cur[NBP];
    int t = threadIdx.x;
    int base = blockIdx.x * CH;
    int n = E - base; if (n > CH) n = CH;

    int er[8], ec[8];
#pragma unroll
    for (int j = 0; j < 8; ++j) {
        int i = t + j * 256;
        if (i < n) { er[j] = row[base + i]; ec[j] = col[base + i]; }
        else er[j] = -1;
    }

    for (int m = 0; m < 2; ++m) {
        cnt[t] = 0;
        __syncthreads();
        uint32 pk[8]; int bk[8];
#pragma unroll
        for (int j = 0; j < 8; ++j) {
            if (er[j] >= 0) {
                int key = m ? er[j] : ec[j];
                int pay = m ? ec[j] : er[j];
                pk[j] = ((uint32)key << 16) | (uint32)pay;
                bk[j] = key >> 8;
                atomicAdd(&cnt[bk[j]], 1);
            }
        }
        __syncthreads();
        int v = cnt[t];
        excl[t] = v;                       // build inclusive scan in excl
        __syncthreads();
        for (int d = 1; d < 256; d <<= 1) {
            int u = (t >= d) ? excl[t - d] : 0;
            __syncthreads();
            excl[t] += u;
            __syncthreads();
        }
        int ex = (t == 0) ? 0 : excl[t - 1];
        __syncthreads();
        excl[t] = ex;
        cur[t] = ex;
        int* gcur = m ? curR : curC;
        run[t] = (v > 0) ? atomicAdd(&gcur[t], v) : 0;
        __syncthreads();
#pragma unroll
        for (int j = 0; j < 8; ++j) {
            if (er[j] >= 0) {
                int pos = atomicAdd(&cur[bk[j]], 1);
                staged[pos] = pk[j];
            }
        }
        __syncthreads();
        uint32* outp = m ? partR : partC;
        for (int i = t; i < n; i += 256) {
            uint32 pv = staged[i];
            int b = pv >> 24;
            outp[run[b] + (i - excl[b])] = pv;
        }
        __syncthreads();
    }
}

// ---------- pass D: per-bucket CSR fill (exclusive write region per block) ----------
__global__ __launch_bounds__(256) void k_fillD(
    const uint32* __restrict__ partC, const uint32* __restrict__ partR,
    const int* __restrict__ bOffC, const int* __restrict__ bOffR,
    int* __restrict__ off_in, int* __restrict__ off_out,
    u16* __restrict__ csr_src, u16* __restrict__ csr_dst,
    int NB, int N, int E) {
    int part = ((int)blockIdx.x >= NB) ? 1 : 0;
    int b = (int)blockIdx.x - part * NB;
    const uint32* arr = part ? partR : partC;
    const int* bOff   = part ? bOffR : bOffC;
    int* offA         = part ? off_out : off_in;
    u16* csr          = part ? csr_dst : csr_src;
    int t = threadIdx.x;
    int base = bOff[b], end = bOff[b + 1];
    __shared__ int cnt[NBP], excl[NBP], cur[NBP];
    cnt[t] = 0;
    __syncthreads();
    for (int i = base + t; i < end; i += 256)
        atomicAdd(&cnt[(arr[i] >> 16) & 255], 1);
    __syncthreads();
    int v = cnt[t];
    excl[t] = v;
    __syncthreads();
    for (int d = 1; d < 256; d <<= 1) {
        int u = (t >= d) ? excl[t - d] : 0;
        __syncthreads();
        excl[t] += u;
        __syncthreads();
    }
    int ex = (t == 0) ? 0 : excl[t - 1];
    __syncthreads();
    excl[t] = ex;
    cur[t] = ex;
    int node = (b << 8) + t;
    if (node < N) offA[node] = base + ex;
    if (b == 0 && t == 0) offA[N] = E;
    __syncthreads();
    for (int i = base + t; i < end; i += 256) {
        uint32 pv = arr[i];
        int local = (pv >> 16) & 255;
        int pos = atomicAdd(&cur[local], 1);
        csr[base + pos] = (u16)(pv & 0xffffu);
    }
}

// ---------- GCN aggregate: out[c] = relu(dinv[c]*(g[c]+sum g[src]) + b) ----------
template <bool OUT_BF16>
__global__ __launch_bounds__(256) void k_agg(
    const uint32* __restrict__ g, const u16* __restrict__ csr_src,
    const int* __restrict__ off, const float* __restrict__ dinv,
    const f32x2* __restrict__ bias, void* __restrict__ outp, int n) {
    int w = (blockIdx.x * 256 + threadIdx.x) >> 6;
    if (w >= n) return;
    int lane = threadIdx.x & 63;
    uint32 sv = g[(size_t)w * 64 + lane];
    float s0 = blo(sv), s1 = bhi(sv);
    int e = off[w], e1 = off[w + 1];
    for (; e + 8 <= e1; e += 8) {
        int ix[8];
#pragma unroll
        for (int j = 0; j < 8; ++j) ix[j] = csr_src[e + j];
        uint32 vv[8];
#pragma unroll
        for (int j = 0; j < 8; ++j) vv[j] = g[(size_t)ix[j] * 64 + lane];
#pragma unroll
        for (int j = 0; j < 8; ++j) { s0 += blo(vv[j]); s1 += bhi(vv[j]); }
    }
    for (; e + 2 <= e1; e += 2) {
        int i0 = csr_src[e], i1 = csr_src[e + 1];
        uint32 v0 = g[(size_t)i0 * 64 + lane];
        uint32 v1 = g[(size_t)i1 * 64 + lane];
        s0 += blo(v0) + blo(v1);
        s1 += bhi(v0) + bhi(v1);
    }
    if (e < e1) {
        uint32 v = g[(size_t)csr_src[e] * 64 + lane];
        s0 += blo(v); s1 += bhi(v);
    }
    float dc = dinv[w];
    f32x2 bb = bias[lane];
    float o0 = fmaxf(fmaf(s0, dc, bb[0]), 0.f);
    float o1 = fmaxf(fmaf(s1, dc, bb[1]), 0.f);
    if (OUT_BF16) {
        ((uint32*)outp)[(size_t)w * 64 + lane] = packbf(o0, o1);
    } else {
        ((f32x2*)outp)[(size_t)w * 64 + lane] = (f32x2){o0, o1};
    }
}

// ---------- neighbor mean ----------
__global__ __launch_bounds__(256) void k_mean(
    const uint32* __restrict__ h, const u16* __restrict__ csr_dst,
    const int* __restrict__ off, f32x2* __restrict__ out, int n) {
    int w = (blockIdx.x * 256 + threadIdx.x) >> 6;
    if (w >= n) return;
    int lane = threadIdx.x & 63;
    int e = off[w], e1 = off[w + 1];
    int d = e1 - e;
    float s0 = 0.f, s1 = 0.f;
    for (; e + 8 <= e1; e += 8) {
        int ix[8];
#pragma unroll
        for (int j = 0; j < 8; ++j) ix[j] = csr_dst[e + j];
        uint32 vv[8];
#pragma unroll
        for (int j = 0; j < 8; ++j) vv[j] = h[(size_t)ix[j] * 64 + lane];
#pragma unroll
        for (int j = 0; j < 8; ++j) { s0 += blo(vv[j]); s1 += bhi(vv[j]); }
    }
    for (; e + 2 <= e1; e += 2) {
        int i0 = csr_dst[e], i1 = csr_dst[e + 1];
        uint32 v0 = h[(size_t)i0 * 64 + lane];
        uint32 v1 = h[(size_t)i1 * 64 + lane];
        s0 += blo(v0) + blo(v1);
        s1 += bhi(v0) + bhi(v1);
    }
    if (e < e1) {
        uint32 v = h[(size_t)csr_dst[e] * 64 + lane];
        s0 += blo(v); s1 += bhi(v);
    }
    f32x2 o;
    if (d > 0) {
        float inv = 1.f / (float)d;
        o[0] = s0 * inv; o[1] = s1 * inv;
    } else {
        uint32 sv = h[(size_t)w * 64 + lane];
        o[0] = blo(sv); o[1] = bhi(sv);
    }
    out[(size_t)w * 64 + lane] = o;
}

// ---------- final: out = (w0*h0 + w1*h1 + w2*h2) @ fcW + fc_b ----------
__global__ __launch_bounds__(256) void k_final(
    const float* __restrict__ h0, const float* __restrict__ h1,
    const float* __restrict__ h2, const float* __restrict__ jkw,
    const u16* __restrict__ fcWTh, const u16* __restrict__ fcWTl,
    const float* __restrict__ fcb, float* __restrict__ out, int M) {
    float a0 = jkw[0], a1 = jkw[1], a2 = jkw[2];
    float mx = fmaxf(a0, fmaxf(a1, a2));
    float e0 = expf(a0 - mx), e1 = expf(a1 - mx), e2 = expf(a2 - mx);
    float inv = 1.f / (e0 + e1 + e2);
    float w0 = e0 * inv, w1 = e1 * inv, w2 = e2 * inv;

    const int wave = threadIdx.x >> 6;
    const int lane = threadIdx.x & 63;
    const int q = lane >> 4, l = lane & 15;
    int rbase = blockIdx.x * 128 + wave * 32;
    if (rbase >= M) return;
    int r0 = rbase + l;      if (r0 >= M) r0 = M - 1;
    int r1 = rbase + 16 + l; if (r1 >= M) r1 = M - 1;

    f32x4 acc[2][4];
#pragma unroll
    for (int i = 0; i < 2; ++i)
#pragma unroll
        for (int j = 0; j < 4; ++j) acc[i][j] = (f32x4){0.f, 0.f, 0.f, 0.f};

#pragma unroll
    for (int kc = 0; kc < 4; ++kc) {
        int k0 = kc * 32 + q * 8;
        bfx8 ah[2], al[2];
        const int rr2[2] = {r0, r1};
#pragma unroll
        for (int half = 0; half < 2; ++half) {
            size_t o = (size_t)rr2[half] * 128 + k0;
            float xx[8];
#pragma unroll
            for (int j = 0; j < 8; ++j)
                xx[j] = w0 * h0[o + j] + w1 * h1[o + j] + w2 * h2[o + j];
            split8v(xx, ah[half], al[half]);
        }
#pragma unroll
        for (int ct = 0; ct < 4; ++ct) {
            bfx8 bh = *(const bfx8*)(fcWTh + (ct * 16 + l) * 128 + k0);
            bfx8 bl = *(const bfx8*)(fcWTl + (ct * 16 + l) * 128 + k0);
#pragma unroll
            for (int half = 0; half < 2; ++half) {
                acc[half][ct] = __builtin_amdgcn_mfma_f32_16x16x32_bf16(ah[half], bh, acc[half][ct], 0, 0, 0);
                acc[half][ct] = __builtin_amdgcn_mfma_f32_16x16x32_bf16(ah[half], bl, acc[half][ct], 0, 0, 0);
                acc[half][ct] = __builtin_amdgcn_mfma_f32_16x16x32_bf16(al[half], bh, acc[half][ct], 0, 0, 0);
            }
        }
    }
#pragma unroll
    for (int rs = 0; rs < 2; ++rs) {
#pragma unroll
        for (int rr = 0; rr < 4; ++rr) {
            int rw = rbase + rs * 16 + q * 4 + rr;
            if (rw < M) {
#pragma unroll
                for (int ct = 0; ct < 4; ++ct) {
                    int cc = ct * 16 + l;
                    out[(size_t)rw * 64 + cc] = acc[rs][ct][rr] + fcb[cc];
                }
            }
        }
    }
}

extern "C" void kernel_launch(void* const* d_in, const int* in_sizes, int n_in,
                              void* d_out, int out_size, void* d_ws, size_t ws_size,
                              hipStream_t stream) {
    const int N = in_sizes[0] / 128;   // 50000
    const int E = in_sizes[1] / 2;     // 800000
    const int NB = (N + 255) >> 8;     // 196 buckets

    const float* x    = (const float*)d_in[0];
    const int* row    = (const int*)d_in[1];
    const int* col    = row + E;
    const float* W1   = (const float*)d_in[2];
    const float* b1   = (const float*)d_in[3];
    const float* W2   = (const float*)d_in[4];
    const float* b2   = (const float*)d_in[5];
    const float* W3   = (const float*)d_in[6];
    const float* b3   = (const float*)d_in[7];
    const float* jkw  = (const float*)d_in[8];
    const float* fcW  = (const float*)d_in[9];
    const float* fcb  = (const float*)d_in[10];
    float* outp       = (float*)d_out;

    char* ws = (char*)d_ws;
    size_t off = 0;
    auto alloc = [&](size_t bytes) -> char* {
        char* p = ws + off;
        off += (bytes + 255) & ~(size_t)255;
        return p;
    };
    // zero-init region: deg_in[N] + cntC[256] + cntR[256]
    int* deg_in = (int*)alloc((size_t)(N + 2 * NBP) * sizeof(int));
    int* cntC   = deg_in + N;
    int* cntR   = cntC + NBP;
    int* bOffC  = (int*)alloc((size_t)(NBP + 1) * sizeof(int));
    int* bOffR  = (int*)alloc((size_t)(NBP + 1) * sizeof(int));
    int* curC   = (int*)alloc((size_t)NBP * sizeof(int));
    int* curR   = (int*)alloc((size_t)NBP * sizeof(int));
    int* off_in  = (int*)alloc((size_t)(N + 1) * sizeof(int));
    int* off_out = (int*)alloc((size_t)(N + 1) * sizeof(int));
    uint32* partC = (uint32*)alloc((size_t)E * sizeof(uint32));
    uint32* partR = (uint32*)alloc((size_t)E * sizeof(uint32));
    u16* csr_src = (u16*)alloc((size_t)E * sizeof(u16));
    u16* csr_dst = (u16*)alloc((size_t)E * sizeof(u16));
    float* dinv  = (float*)alloc((size_t)N * sizeof(float));
    const int WTN = 3 * 16384 + 8192;
    u16* WTh = (u16*)alloc((size_t)WTN * sizeof(u16));
    u16* WTl = (u16*)alloc((size_t)WTN * sizeof(u16));
    u16* gbuf = (u16*)alloc((size_t)N * 128 * sizeof(u16));
    u16* t0   = (u16*)alloc((size_t)N * 128 * sizeof(u16));
    float* h0 = (float*)alloc((size_t)N * 128 * sizeof(float));
    float* h1 = (float*)alloc((size_t)N * 128 * sizeof(float));
    float* h2 = (float*)alloc((size_t)N * 128 * sizeof(float));

    hipMemsetAsync(deg_in, 0, (size_t)(N + 2 * NBP) * sizeof(int), stream);

    const int B = 256;
    int Gh = (E + CH - 1) / CH;               // 391 histogram blocks
    int Gwt = (WTN + B - 1) / B;              // 224 weight-split blocks
    k_preA<<<Gh + Gwt, B, 0, stream>>>(row, col, E, Gh, cntC, cntR, deg_in,
                                       W1, W2, W3, fcW, WTh, WTl, WTN);
    k_scanB<<<1 + (N + B - 1) / B, B, 0, stream>>>(cntC, cntR, bOffC, bOffR,
                                                   curC, curR, deg_in, dinv, NB, N);

    int Gc = (E + CH - 1) / CH;               // partition blocks
    int Gg = (N + 127) / 128;                 // gemm blocks
    k_partC_gemm0<<<Gc + Gg, B, 0, stream>>>(row, col, E, Gc, curC, curR, partC, partR,
                                             x, WTh, WTl, dinv, gbuf, N);
    k_fillD<<<2 * NB, B, 0, stream>>>(partC, partR, bOffC, bOffR,
                                      off_in, off_out, csr_src, csr_dst, NB, N, E);

    int aggG = (N + 3) / 4;                   // 4 waves/block, 1 node/wave

    // layer 0
    k_agg<true><<<aggG, B, 0, stream>>>((const uint32*)gbuf, csr_src, off_in, dinv,
                                        (const f32x2*)b1, (void*)t0, N);
    k_mean<<<aggG, B, 0, stream>>>((const uint32*)t0, csr_dst, off_out, (f32x2*)h0, N);
    // layer 1
    k_gemm128<<<Gg, B, 0, stream>>>(h0, WTh + 16384, WTl + 16384, dinv, gbuf, N);
    k_agg<false><<<aggG, B, 0, stream>>>((const uint32*)gbuf, csr_src, off_in, dinv,
                                         (const f32x2*)b2, (void*)h1, N);
    // layer 2
    k_gemm128<<<Gg, B, 0, stream>>>(h1, WTh + 2 * 16384, WTl + 2 * 16384, dinv, gbuf, N);
    k_agg<false><<<aggG, B, 0, stream>>>((const uint32*)gbuf, csr_src, off_in, dinv,
                                         (const f32x2*)b3, (void*)h2, N);
    // JK combine + final linear
    k_final<<<Gg, B, 0, stream>>>(h0, h1, h2, jkw, WTh + 3 * 16384, WTl + 3 * 16384,
                                  fcb, outp, N);
}

// Round 5
// 387.961 us; speedup vs baseline: 1.6272x; 1.0048x over previous
//
#include <hip/hip_runtime.h>
#include <stdint.h>

typedef unsigned int  uint32;
typedef unsigned short u16;

typedef short bfx8 __attribute__((ext_vector_type(8)));
typedef float f32x4 __attribute__((ext_vector_type(4)));
typedef float f32x2 __attribute__((ext_vector_type(2)));

#define NBP 256          // padded bucket count (N <= 65536)
#define CH  2048         // edges per partition chunk

// ---------- bf16 helpers ----------
__device__ __forceinline__ float b2f(u16 u) {
    union { uint32 i; float f; } v; v.i = ((uint32)u) << 16; return v.f;
}
__device__ __forceinline__ u16 f2b(float f) {
    union { float f; uint32 i; } v; v.f = f;
    uint32 u = v.i;
    return (u16)((u + 0x7fffu + ((u >> 16) & 1u)) >> 16);   // RNE
}
__device__ __forceinline__ float blo(uint32 u) {
    union { uint32 i; float f; } v; v.i = u << 16; return v.f;
}
__device__ __forceinline__ float bhi(uint32 u) {
    union { uint32 i; float f; } v; v.i = u & 0xffff0000u; return v.f;
}
__device__ __forceinline__ uint32 packbf(float a, float b) {
    return (uint32)f2b(a) | ((uint32)f2b(b) << 16);
}
// split fp32 -> hi/lo bf16
__device__ __forceinline__ void splitf(float x, u16& h, u16& l) {
    h = f2b(x);
    l = f2b(x - b2f(h));
}
__device__ __forceinline__ void split8(const float* __restrict__ p, bfx8& hi, bfx8& lo) {
    f32x4 a = *(const f32x4*)p;
    f32x4 b = *(const f32x4*)(p + 4);
    float x[8] = {a[0], a[1], a[2], a[3], b[0], b[1], b[2], b[3]};
#pragma unroll
    for (int j = 0; j < 8; ++j) {
        u16 h, l; splitf(x[j], h, l);
        hi[j] = (short)h; lo[j] = (short)l;
    }
}

// ---------- pass A: packed bucket histograms + per-node deg_in || weight split ----------
__global__ __launch_bounds__(256) void k_preA(
    const int* __restrict__ row, const int* __restrict__ col, int E, int Gh,
    int* __restrict__ cntC, int* __restrict__ cntR, int* __restrict__ deg_in,
    const float* __restrict__ W1, const float* __restrict__ W2,
    const float* __restrict__ W3, const float* __restrict__ fcW,
    u16* __restrict__ WTh, u16* __restrict__ WTl, int WTN) {
    if ((int)blockIdx.x < Gh) {
        __shared__ int hp[NBP];        // packed: col-count low16, row-count high16
        int t = threadIdx.x;
        hp[t] = 0;
        __syncthreads();
        int base = blockIdx.x * CH;
        int n = E - base; if (n > CH) n = CH;
        for (int i = t; i < n; i += 256) {
            int r = row[base + i], c = col[base + i];
            atomicAdd(&hp[c >> 8], 1);
            atomicAdd(&hp[r >> 8], 0x10000);
            atomicAdd(&deg_in[c], 1);
        }
        __syncthreads();
        int v = hp[t];
        if (v & 0xffff) atomicAdd(&cntC[t], v & 0xffff);
        if (v >> 16)    atomicAdd(&cntR[t], v >> 16);
        return;
    }
    int i = ((int)blockIdx.x - Gh) * 256 + threadIdx.x;
    if (i >= WTN) return;
    float w;
    if (i < 3 * 16384) {
        int m = i >> 14, j = i & 16383;     // j = fo*128 + fi
        int fo = j >> 7, fi = j & 127;
        const float* W = (m == 0) ? W1 : (m == 1) ? W2 : W3;
        w = W[fi * 128 + fo];
    } else {
        int j = i - 3 * 16384;
        int fo = j >> 7, fi = j & 127;
        w = fcW[fi * 64 + fo];
    }
    u16 h, l; splitf(w, h, l);
    WTh[i] = h; WTl[i] = l;
}

// ---------- pass B: block 0 scans bucket counts -> offsets+cursors; rest: dinv ----------
__global__ __launch_bounds__(256) void k_scanB(
    const int* __restrict__ cntC, const int* __restrict__ cntR,
    int* __restrict__ bOffC, int* __restrict__ bOffR,
    int* __restrict__ curC, int* __restrict__ curR,
    const int* __restrict__ deg_in, float* __restrict__ dinv, int NB, int N) {
    int t = threadIdx.x;
    if (blockIdx.x >= 1) {
        int i = ((int)blockIdx.x - 1) * 256 + t;
        if (i < N) dinv[i] = rsqrtf((float)(deg_in[i] + 1));   // +1 self loop
        return;
    }
    int lane = t & 63, wid = t >> 6;
    __shared__ int wsum[4];
    for (int m = 0; m < 2; ++m) {
        const int* cnt = m ? cntR : cntC;
        int* bOff = m ? bOffR : bOffC;
        int* cur  = m ? curR  : curC;
        int v = (t < NB) ? cnt[t] : 0;
        int x = v;
#pragma unroll
        for (int d = 1; d < 64; d <<= 1) {
            int u = __shfl_up(x, d);
            if (lane >= d) x += u;
        }
        if (lane == 63) wsum[wid] = x;
        __syncthreads();
        int add = 0;
        for (int i = 0; i < wid; ++i) add += wsum[i];
        int ex = x + add - v;
        if (t <= NB) bOff[t] = ex;
        cur[t] = ex;
        __syncthreads();
    }
}

// ---------- gemm body (fp32 A, split in-kernel): G = (A @ W) * dinv, bf16 out ----------
__device__ __forceinline__ void gemm128_f32_body(
    const float* __restrict__ A, const u16* __restrict__ WTh, const u16* __restrict__ WTl,
    const float* __restrict__ dinv, u16* __restrict__ G, int M, int blk) {
    const int lane = threadIdx.x & 63;
    const int q = lane >> 4, l = lane & 15;
    int rbase = blk * 128 + (threadIdx.x >> 6) * 32;
    if (rbase >= M) return;
    int r0 = rbase + l;      if (r0 >= M) r0 = M - 1;
    int r1 = rbase + 16 + l; if (r1 >= M) r1 = M - 1;

    f32x4 acc[2][8];
#pragma unroll
    for (int i = 0; i < 2; ++i)
#pragma unroll
        for (int j = 0; j < 8; ++j) acc[i][j] = (f32x4){0.f, 0.f, 0.f, 0.f};

#pragma unroll
    for (int kc = 0; kc < 4; ++kc) {
        int k0 = kc * 32 + q * 8;
        bfx8 ah0, al0, ah1, al1;
        split8(A + (size_t)r0 * 128 + k0, ah0, al0);
        split8(A + (size_t)r1 * 128 + k0, ah1, al1);
#pragma unroll
        for (int ct = 0; ct < 8; ++ct) {
            bfx8 bh = *(const bfx8*)(WTh + (ct * 16 + l) * 128 + k0);
            bfx8 bl = *(const bfx8*)(WTl + (ct * 16 + l) * 128 + k0);
            acc[0][ct] = __builtin_amdgcn_mfma_f32_16x16x32_bf16(ah0, bh, acc[0][ct], 0, 0, 0);
            acc[0][ct] = __builtin_amdgcn_mfma_f32_16x16x32_bf16(ah0, bl, acc[0][ct], 0, 0, 0);
            acc[0][ct] = __builtin_amdgcn_mfma_f32_16x16x32_bf16(al0, bh, acc[0][ct], 0, 0, 0);
            acc[1][ct] = __builtin_amdgcn_mfma_f32_16x16x32_bf16(ah1, bh, acc[1][ct], 0, 0, 0);
            acc[1][ct] = __builtin_amdgcn_mfma_f32_16x16x32_bf16(ah1, bl, acc[1][ct], 0, 0, 0);
            acc[1][ct] = __builtin_amdgcn_mfma_f32_16x16x32_bf16(al1, bh, acc[1][ct], 0, 0, 0);
        }
    }
#pragma unroll
    for (int rs = 0; rs < 2; ++rs) {
#pragma unroll
        for (int rr = 0; rr < 4; ++rr) {
            int rw = rbase + rs * 16 + q * 4 + rr;
            if (rw < M) {
                float dv = dinv[rw];
#pragma unroll
                for (int ct = 0; ct < 8; ++ct)
                    G[(size_t)rw * 128 + ct * 16 + l] = f2b(acc[rs][ct][rr] * dv);
            }
        }
    }
}

// ---------- gemm from hi/lo bf16 planes (no split VALU): G = (A @ W) * dinv ----------
__global__ __launch_bounds__(256) void k_gemm128_pl(
    const u16* __restrict__ Ah, const u16* __restrict__ Al,
    const u16* __restrict__ WTh, const u16* __restrict__ WTl,
    const float* __restrict__ dinv, u16* __restrict__ G, int M) {
    const int lane = threadIdx.x & 63;
    const int q = lane >> 4, l = lane & 15;
    int rbase = blockIdx.x * 128 + (threadIdx.x >> 6) * 32;
    if (rbase >= M) return;
    int r0 = rbase + l;      if (r0 >= M) r0 = M - 1;
    int r1 = rbase + 16 + l; if (r1 >= M) r1 = M - 1;

    f32x4 acc[2][8];
#pragma unroll
    for (int i = 0; i < 2; ++i)
#pragma unroll
        for (int j = 0; j < 8; ++j) acc[i][j] = (f32x4){0.f, 0.f, 0.f, 0.f};

#pragma unroll
    for (int kc = 0; kc < 4; ++kc) {
        int k0 = kc * 32 + q * 8;
        bfx8 ah0 = *(const bfx8*)(Ah + (size_t)r0 * 128 + k0);
        bfx8 al0 = *(const bfx8*)(Al + (size_t)r0 * 128 + k0);
        bfx8 ah1 = *(const bfx8*)(Ah + (size_t)r1 * 128 + k0);
        bfx8 al1 = *(const bfx8*)(Al + (size_t)r1 * 128 + k0);
#pragma unroll
        for (int ct = 0; ct < 8; ++ct) {
            bfx8 bh = *(const bfx8*)(WTh + (ct * 16 + l) * 128 + k0);
            bfx8 bl = *(const bfx8*)(WTl + (ct * 16 + l) * 128 + k0);
            acc[0][ct] = __builtin_amdgcn_mfma_f32_16x16x32_bf16(ah0, bh, acc[0][ct], 0, 0, 0);
            acc[0][ct] = __builtin_amdgcn_mfma_f32_16x16x32_bf16(ah0, bl, acc[0][ct], 0, 0, 0);
            acc[0][ct] = __builtin_amdgcn_mfma_f32_16x16x32_bf16(al0, bh, acc[0][ct], 0, 0, 0);
            acc[1][ct] = __builtin_amdgcn_mfma_f32_16x16x32_bf16(ah1, bh, acc[1][ct], 0, 0, 0);
            acc[1][ct] = __builtin_amdgcn_mfma_f32_16x16x32_bf16(ah1, bl, acc[1][ct], 0, 0, 0);
            acc[1][ct] = __builtin_amdgcn_mfma_f32_16x16x32_bf16(al1, bh, acc[1][ct], 0, 0, 0);
        }
    }
#pragma unroll
    for (int rs = 0; rs < 2; ++rs) {
#pragma unroll
        for (int rr = 0; rr < 4; ++rr) {
            int rw = rbase + rs * 16 + q * 4 + rr;
            if (rw < M) {
                float dv = dinv[rw];
#pragma unroll
                for (int ct = 0; ct < 8; ++ct)
                    G[(size_t)rw * 128 + ct * 16 + l] = f2b(acc[rs][ct][rr] * dv);
            }
        }
    }
}

// ---------- pass C: dual-direction bucket partition (blocks < Gc) || gemm0 ----------
__global__ __launch_bounds__(256) void k_partC_gemm0(
    const int* __restrict__ row, const int* __restrict__ col, int E, int Gc,
    int* __restrict__ curC, int* __restrict__ curR,
    uint32* __restrict__ partC, uint32* __restrict__ partR,
    const float* __restrict__ A, const u16* __restrict__ WTh, const u16* __restrict__ WTl,
    const float* __restrict__ dinv, u16* __restrict__ G, int M) {
    if ((int)blockIdx.x >= Gc) {
        gemm128_f32_body(A, WTh, WTl, dinv, G, M, (int)blockIdx.x - Gc);
        return;
    }
    __shared__ uint32 stagedC[CH], stagedR[CH];
    __shared__ int hp[NBP], expk[NBP], curp[NBP], runC[NBP], runR[NBP];
    __shared__ int wsum[4];
    int t = threadIdx.x;
    int lane = t & 63, wid = t >> 6;
    int base = blockIdx.x * CH;
    int n = E - base; if (n > CH) n = CH;

    int er[8], ec[8];
#pragma unroll
    for (int j = 0; j < 8; ++j) {
        int i = t + j * 256;
        if (i < n) { er[j] = row[base + i]; ec[j] = col[base + i]; }
        else er[j] = -1;
    }
    hp[t] = 0;
    __syncthreads();
#pragma unroll
    for (int j = 0; j < 8; ++j) {
        if (er[j] >= 0) {
            atomicAdd(&hp[ec[j] >> 8], 1);         // col-keyed count (low16)
            atomicAdd(&hp[er[j] >> 8], 0x10000);   // row-keyed count (high16)
        }
    }
    __syncthreads();
    int v = hp[t];
    // packed wave scan over 256 buckets (fields < 2^16: no carry)
    int x = v;
#pragma unroll
    for (int d = 1; d < 64; d <<= 1) {
        int u = __shfl_up(x, d);
        if (lane >= d) x += u;
    }
    if (lane == 63) wsum[wid] = x;
    __syncthreads();
    int add = 0;
    for (int i = 0; i < wid; ++i) add += wsum[i];
    int ex = x + add - v;              // packed exclusive prefix
    expk[t] = ex;
    curp[t] = ex;
    int vC = v & 0xffff, vR = v >> 16;
    runC[t] = vC ? atomicAdd(&curC[t], vC) : 0;    // global claim (cur pre-inited to bOff)
    runR[t] = vR ? atomicAdd(&curR[t], vR) : 0;
    __syncthreads();
#pragma unroll
    for (int j = 0; j < 8; ++j) {
        if (er[j] >= 0) {
            int cb = ec[j] >> 8, rb = er[j] >> 8;
            int pC = atomicAdd(&curp[cb], 1) & 0xffff;
            stagedC[pC] = ((uint32)ec[j] << 16) | (uint32)er[j];
            int pR = atomicAdd(&curp[rb], 0x10000) >> 16;
            stagedR[pR] = ((uint32)er[j] << 16) | (uint32)ec[j];
        }
    }
    __syncthreads();
    for (int i = t; i < n; i += 256) {
        uint32 pv = stagedC[i];
        int b = pv >> 24;
        partC[runC[b] + (i - (expk[b] & 0xffff))] = pv;
    }
    for (int i = t; i < n; i += 256) {
        uint32 pv = stagedR[i];
        int b = pv >> 24;
        partR[runR[b] + (i - (expk[b] >> 16))] = pv;
    }
}

// ---------- pass D: per-bucket CSR fill (exclusive write region per block) ----------
__global__ __launch_bounds__(256) void k_fillD(
    const uint32* __restrict__ partC, const uint32* __restrict__ partR,
    const int* __restrict__ bOffC, const int* __restrict__ bOffR,
    int* __restrict__ off_in, int* __restrict__ off_out,
    u16* __restrict__ csr_src, u16* __restrict__ csr_dst,
    int NB, int N, int E) {
    int part = ((int)blockIdx.x >= NB) ? 1 : 0;
    int b = (int)blockIdx.x - part * NB;
    const uint32* arr = part ? partR : partC;
    const int* bOff   = part ? bOffR : bOffC;
    int* offA         = part ? off_out : off_in;
    u16* csr          = part ? csr_dst : csr_src;
    int t = threadIdx.x;
    int lane = t & 63, wid = t >> 6;
    int base = bOff[b], end = bOff[b + 1];
    __shared__ int cnt[NBP], cur[NBP];
    __shared__ int wsum[4];
    cnt[t] = 0;
    __syncthreads();
    for (int i = base + t; i < end; i += 256)
        atomicAdd(&cnt[(arr[i] >> 16) & 255], 1);
    __syncthreads();
    int v = cnt[t];
    int x = v;
#pragma unroll
    for (int d = 1; d < 64; d <<= 1) {
        int u = __shfl_up(x, d);
        if (lane >= d) x += u;
    }
    if (lane == 63) wsum[wid] = x;
    __syncthreads();
    int add = 0;
    for (int i = 0; i < wid; ++i) add += wsum[i];
    int ex = x + add - v;
    cur[t] = ex;
    int node = (b << 8) + t;
    if (node < N) offA[node] = base + ex;
    if (b == 0 && t == 0) offA[N] = E;
    __syncthreads();
    for (int i = base + t; i < end; i += 256) {
        uint32 pv = arr[i];
        int local = (pv >> 16) & 255;
        int pos = atomicAdd(&cur[local], 1);
        csr[base + pos] = (u16)(pv & 0xffffu);
    }
}

// ---------- GCN aggregate: out[c] = relu(dinv[c]*(g[c]+sum g[src]) + b) ----------
// MODE 0: single bf16 plane out; MODE 1: hi/lo bf16 plane out
template <int MODE>
__global__ __launch_bounds__(256) void k_agg(
    const uint32* __restrict__ g, const u16* __restrict__ csr_src,
    const int* __restrict__ off, const float* __restrict__ dinv,
    const f32x2* __restrict__ bias, uint32* __restrict__ outH,
    uint32* __restrict__ outL, int n) {
    int w = (blockIdx.x * 256 + threadIdx.x) >> 6;
    if (w >= n) return;
    int lane = threadIdx.x & 63;
    uint32 sv = g[(size_t)w * 64 + lane];
    float s0 = blo(sv), s1 = bhi(sv);
    int e = off[w], e1 = off[w + 1];
    for (; e + 8 <= e1; e += 8) {
        int ix[8];
#pragma unroll
        for (int j = 0; j < 8; ++j) ix[j] = csr_src[e + j];
        uint32 vv[8];
#pragma unroll
        for (int j = 0; j < 8; ++j) vv[j] = g[(size_t)ix[j] * 64 + lane];
#pragma unroll
        for (int j = 0; j < 8; ++j) { s0 += blo(vv[j]); s1 += bhi(vv[j]); }
    }
    for (; e + 2 <= e1; e += 2) {
        int i0 = csr_src[e], i1 = csr_src[e + 1];
        uint32 v0 = g[(size_t)i0 * 64 + lane];
        uint32 v1 = g[(size_t)i1 * 64 + lane];
        s0 += blo(v0) + blo(v1);
        s1 += bhi(v0) + bhi(v1);
    }
    if (e < e1) {
        uint32 v = g[(size_t)csr_src[e] * 64 + lane];
        s0 += blo(v); s1 += bhi(v);
    }
    float dc = dinv[w];
    f32x2 bb = bias[lane];
    float o0 = fmaxf(fmaf(s0, dc, bb[0]), 0.f);
    float o1 = fmaxf(fmaf(s1, dc, bb[1]), 0.f);
    if (MODE == 0) {
        outH[(size_t)w * 64 + lane] = packbf(o0, o1);
    } else {
        u16 h0, l0, h1, l1;
        splitf(o0, h0, l0);
        splitf(o1, h1, l1);
        outH[(size_t)w * 64 + lane] = (uint32)h0 | ((uint32)h1 << 16);
        outL[(size_t)w * 64 + lane] = (uint32)l0 | ((uint32)l1 << 16);
    }
}

// ---------- neighbor mean over bf16 t0 -> hi/lo planes ----------
__global__ __launch_bounds__(256) void k_mean(
    const uint32* __restrict__ h, const u16* __restrict__ csr_dst,
    const int* __restrict__ off, uint32* __restrict__ outH,
    uint32* __restrict__ outL, int n) {
    int w = (blockIdx.x * 256 + threadIdx.x) >> 6;
    if (w >= n) return;
    int lane = threadIdx.x & 63;
    int e = off[w], e1 = off[w + 1];
    int d = e1 - e;
    float s0 = 0.f, s1 = 0.f;
    for (; e + 8 <= e1; e += 8) {
        int ix[8];
#pragma unroll
        for (int j = 0; j < 8; ++j) ix[j] = csr_dst[e + j];
        uint32 vv[8];
#pragma unroll
        for (int j = 0; j < 8; ++j) vv[j] = h[(size_t)ix[j] * 64 + lane];
#pragma unroll
        for (int j = 0; j < 8; ++j) { s0 += blo(vv[j]); s1 += bhi(vv[j]); }
    }
    for (; e + 2 <= e1; e += 2) {
        int i0 = csr_dst[e], i1 = csr_dst[e + 1];
        uint32 v0 = h[(size_t)i0 * 64 + lane];
        uint32 v1 = h[(size_t)i1 * 64 + lane];
        s0 += blo(v0) + blo(v1);
        s1 += bhi(v0) + bhi(v1);
    }
    if (e < e1) {
        uint32 v = h[(size_t)csr_dst[e] * 64 + lane];
        s0 += blo(v); s1 += bhi(v);
    }
    float o0, o1;
    if (d > 0) {
        float inv = 1.f / (float)d;
        o0 = s0 * inv; o1 = s1 * inv;
    } else {
        uint32 sv = h[(size_t)w * 64 + lane];
        o0 = blo(sv); o1 = bhi(sv);
    }
    u16 ha, la, hb, lb;
    splitf(o0, ha, la);
    splitf(o1, hb, lb);
    outH[(size_t)w * 64 + lane] = (uint32)ha | ((uint32)hb << 16);
    outL[(size_t)w * 64 + lane] = (uint32)la | ((uint32)lb << 16);
}

// ---------- final: out = (w0*h0 + w1*h1 + w2*h2) @ fcW + fc_b ----------
__global__ __launch_bounds__(256) void k_final(
    const u16* __restrict__ h0h, const u16* __restrict__ h0l,
    const u16* __restrict__ h1h, const u16* __restrict__ h1l,
    const u16* __restrict__ h2h, const u16* __restrict__ h2l,
    const float* __restrict__ jkw,
    const u16* __restrict__ fcWTh, const u16* __restrict__ fcWTl,
    const float* __restrict__ fcb, float* __restrict__ out, int M) {
    float a0 = jkw[0], a1 = jkw[1], a2 = jkw[2];
    float mx = fmaxf(a0, fmaxf(a1, a2));
    float e0 = expf(a0 - mx), e1 = expf(a1 - mx), e2 = expf(a2 - mx);
    float inv = 1.f / (e0 + e1 + e2);
    float w0 = e0 * inv, w1 = e1 * inv, w2 = e2 * inv;

    const int lane = threadIdx.x & 63;
    const int q = lane >> 4, l = lane & 15;
    int rbase = blockIdx.x * 128 + (threadIdx.x >> 6) * 32;
    if (rbase >= M) return;
    int r0 = rbase + l;      if (r0 >= M) r0 = M - 1;
    int r1 = rbase + 16 + l; if (r1 >= M) r1 = M - 1;

    f32x4 acc[2][4];
#pragma unroll
    for (int i = 0; i < 2; ++i)
#pragma unroll
        for (int j = 0; j < 4; ++j) acc[i][j] = (f32x4){0.f, 0.f, 0.f, 0.f};

    union U8 { bfx8 v; u16 u[8]; };

#pragma unroll
    for (int kc = 0; kc < 4; ++kc) {
        int k0 = kc * 32 + q * 8;
        bfx8 ah[2], al[2];
        const int rr2[2] = {r0, r1};
#pragma unroll
        for (int half = 0; half < 2; ++half) {
            size_t o = (size_t)rr2[half] * 128 + k0;
            U8 x0h, x0l, x1h, x1l, x2h, x2l, rh, rl;
            x0h.v = *(const bfx8*)(h0h + o); x0l.v = *(const bfx8*)(h0l + o);
            x1h.v = *(const bfx8*)(h1h + o); x1l.v = *(const bfx8*)(h1l + o);
            x2h.v = *(const bfx8*)(h2h + o); x2l.v = *(const bfx8*)(h2l + o);
#pragma unroll
            for (int j = 0; j < 8; ++j) {
                float v0 = b2f(x0h.u[j]) + b2f(x0l.u[j]);
                float v1 = b2f(x1h.u[j]) + b2f(x1l.u[j]);
                float v2 = b2f(x2h.u[j]) + b2f(x2l.u[j]);
                float c = w0 * v0 + w1 * v1 + w2 * v2;
                u16 ch, cl; splitf(c, ch, cl);
                rh.u[j] = ch; rl.u[j] = cl;
            }
            ah[half] = rh.v; al[half] = rl.v;
        }
#pragma unroll
        for (int ct = 0; ct < 4; ++ct) {
            bfx8 bh = *(const bfx8*)(fcWTh + (ct * 16 + l) * 128 + k0);
            bfx8 bl = *(const bfx8*)(fcWTl + (ct * 16 + l) * 128 + k0);
#pragma unroll
            for (int half = 0; half < 2; ++half) {
                acc[half][ct] = __builtin_amdgcn_mfma_f32_16x16x32_bf16(ah[half], bh, acc[half][ct], 0, 0, 0);
                acc[half][ct] = __builtin_amdgcn_mfma_f32_16x16x32_bf16(ah[half], bl, acc[half][ct], 0, 0, 0);
                acc[half][ct] = __builtin_amdgcn_mfma_f32_16x16x32_bf16(al[half], bh, acc[half][ct], 0, 0, 0);
            }
        }
    }
#pragma unroll
    for (int rs = 0; rs < 2; ++rs) {
#pragma unroll
        for (int rr = 0; rr < 4; ++rr) {
            int rw = rbase + rs * 16 + q * 4 + rr;
            if (rw < M) {
#pragma unroll
                for (int ct = 0; ct < 4; ++ct) {
                    int cc = ct * 16 + l;
                    out[(size_t)rw * 64 + cc] = acc[rs][ct][rr] + fcb[cc];
                }
            }
        }
    }
}

extern "C" void kernel_launch(void* const* d_in, const int* in_sizes, int n_in,
                              void* d_out, int out_size, void* d_ws, size_t ws_size,
                              hipStream_t stream) {
    const int N = in_sizes[0] / 128;   // 50000
    const int E = in_sizes[1] / 2;     // 800000
    const int NB = (N + 255) >> 8;     // 196 buckets

    const float* x    = (const float*)d_in[0];
    const int* row    = (const int*)d_in[1];
    const int* col    = row + E;
    const float* W1   = (const float*)d_in[2];
    const float* b1   = (const float*)d_in[3];
    const float* W2   = (const float*)d_in[4];
    const float* b2   = (const float*)d_in[5];
    const float* W3   = (const float*)d_in[6];
    const float* b3   = (const float*)d_in[7];
    const float* jkw  = (const float*)d_in[8];
    const float* fcW  = (const float*)d_in[9];
    const float* fcb  = (const float*)d_in[10];
    float* outp       = (float*)d_out;

    char* ws = (char*)d_ws;
    size_t off = 0;
    auto alloc = [&](size_t bytes) -> char* {
        char* p = ws + off;
        off += (bytes + 255) & ~(size_t)255;
        return p;
    };
    // zero-init region: deg_in[N] + cntC + cntR
    int* deg_in = (int*)alloc((size_t)(N + 2 * NBP) * sizeof(int));
    int* cntC   = deg_in + N;
    int* cntR   = cntC + NBP;
    int* bOffC  = (int*)alloc((size_t)(NBP + 1) * sizeof(int));
    int* bOffR  = (int*)alloc((size_t)(NBP + 1) * sizeof(int));
    int* curC   = (int*)alloc((size_t)NBP * sizeof(int));
    int* curR   = (int*)alloc((size_t)NBP * sizeof(int));
    int* off_in  = (int*)alloc((size_t)(N + 1) * sizeof(int));
    int* off_out = (int*)alloc((size_t)(N + 1) * sizeof(int));
    uint32* partC = (uint32*)alloc((size_t)E * sizeof(uint32));
    uint32* partR = (uint32*)alloc((size_t)E * sizeof(uint32));
    u16* csr_src = (u16*)alloc((size_t)E * sizeof(u16));
    u16* csr_dst = (u16*)alloc((size_t)E * sizeof(u16));
    float* dinv  = (float*)alloc((size_t)N * sizeof(float));
    const int WTN = 3 * 16384 + 8192;
    u16* WTh = (u16*)alloc((size_t)WTN * sizeof(u16));
    u16* WTl = (u16*)alloc((size_t)WTN * sizeof(u16));
    size_t FB = (size_t)N * 128 * sizeof(u16);
    u16* gbuf = (u16*)alloc(FB);       // bf16 gemm out (gathered; reused x3)
    u16* t0   = (u16*)alloc(FB);       // bf16 pre-mean temp (gathered)
    u16* h0h = (u16*)alloc(FB); u16* h0l = (u16*)alloc(FB);
    u16* h1h = (u16*)alloc(FB); u16* h1l = (u16*)alloc(FB);
    u16* h2h = (u16*)alloc(FB); u16* h2l = (u16*)alloc(FB);

    hipMemsetAsync(deg_in, 0, (size_t)(N + 2 * NBP) * sizeof(int), stream);

    const int B = 256;
    int Gh = (E + CH - 1) / CH;               // histogram blocks
    int Gwt = (WTN + B - 1) / B;              // weight-split blocks
    k_preA<<<Gh + Gwt, B, 0, stream>>>(row, col, E, Gh, cntC, cntR, deg_in,
                                       W1, W2, W3, fcW, WTh, WTl, WTN);
    k_scanB<<<1 + (N + B - 1) / B, B, 0, stream>>>(cntC, cntR, bOffC, bOffR,
                                                   curC, curR, deg_in, dinv, NB, N);

    int Gc = (E + CH - 1) / CH;               // partition blocks
    int Gg = (N + 127) / 128;                 // gemm blocks
    k_partC_gemm0<<<Gc + Gg, B, 0, stream>>>(row, col, E, Gc, curC, curR, partC, partR,
                                             x, WTh, WTl, dinv, gbuf, N);
    k_fillD<<<2 * NB, B, 0, stream>>>(partC, partR, bOffC, bOffR,
                                      off_in, off_out, csr_src, csr_dst, NB, N, E);

    int aggG = (N + 3) / 4;                   // 4 waves/block, 1 node/wave

    // layer 0
    k_agg<0><<<aggG, B, 0, stream>>>((const uint32*)gbuf, csr_src, off_in, dinv,
                                     (const f32x2*)b1, (uint32*)t0, nullptr, N);
    k_mean<<<aggG, B, 0, stream>>>((const uint32*)t0, csr_dst, off_out,
                                   (uint32*)h0h, (uint32*)h0l, N);
    // layer 1
    k_gemm128_pl<<<Gg, B, 0, stream>>>(h0h, h0l, WTh + 16384, WTl + 16384, dinv, gbuf, N);
    k_agg<1><<<aggG, B, 0, stream>>>((const uint32*)gbuf, csr_src, off_in, dinv,
                                     (const f32x2*)b2, (uint32*)h1h, (uint32*)h1l, N);
    // layer 2
    k_gemm128_pl<<<Gg, B, 0, stream>>>(h1h, h1l, WTh + 2 * 16384, WTl + 2 * 16384, dinv, gbuf, N);
    k_agg<1><<<aggG, B, 0, stream>>>((const uint32*)gbuf, csr_src, off_in, dinv,
                                     (const f32x2*)b3, (uint32*)h2h, (uint32*)h2l, N);
    // JK combine + final linear
    k_final<<<Gg, B, 0, stream>>>(h0h, h0l, h1h, h1l, h2h, h2l, jkw,
                                  WTh + 3 * 16384, WTl + 3 * 16384, fcb, outp, N);
}